// Round 10
// baseline (693.053 us; speedup 1.0000x reference)
//
#include <hip/hip_runtime.h>
#include <hip/hip_bf16.h>
#include <math.h>

#define B_SZ   256
#define D_DIM  256
#define C_DIM  64
#define N_CAND 200000
#define K_TOP  5
#define CHUNK  64
#define NCHGLB (N_CAND / CHUNK)               // 3125 bank chunks (exact)
#define CHUNK_SH 16384                        // shorts per permuted 64-row chunk (32KB)
#define NCHJ1  8                              // chunks per job, pass 1
#define NCHJ2  16                             // chunks per job, pass 2
#define S1     ((NCHGLB + NCHJ1 - 1) / NCHJ1) // 391 jobs (last = 5 chunks)
#define S2     ((NCHGLB + NCHJ2 - 1) / NCHJ2) // 196 jobs (last = 5 chunks)

typedef short bf16x8 __attribute__((ext_vector_type(8)));
typedef float f32x16 __attribute__((ext_vector_type(16)));
typedef unsigned short u16x8 __attribute__((ext_vector_type(8)));

__device__ __forceinline__ bool better(float v1, int i1, float v2, int i2) {
    return (v1 > v2) || (v1 == v2 && i1 < i2);
}

__device__ __forceinline__ void insert6(float* lv, int* li, float v, int idx) {
    if (better(v, idx, lv[5], li[5])) {
        lv[5] = v; li[5] = idx;
        #pragma unroll
        for (int k = 5; k > 0; --k) {
            if (better(lv[k], li[k], lv[k - 1], li[k - 1])) {
                float tv = lv[k]; lv[k] = lv[k - 1]; lv[k - 1] = tv;
                int   ti = li[k]; li[k] = li[k - 1]; li[k - 1] = ti;
            }
        }
    }
}

__device__ __forceinline__ void merge6(const float* av, const int* ai,
                                       const float* bv, const int* bi,
                                       float* ov, int* oi) {
    int ia = 0, ib = 0;
    #pragma unroll
    for (int k = 0; k < 6; ++k) {
        bool ta;
        if (ia >= 6)      ta = false;
        else if (ib >= 6) ta = true;
        else              ta = better(av[ia], ai[ia], bv[ib], bi[ib]);
        if (ta) { ov[k] = av[ia]; oi[k] = ai[ia]; ++ia; }
        else    { ov[k] = bv[ib]; oi[k] = bi[ib]; ++ib; }
    }
}

__device__ __forceinline__ unsigned short bf16rne(float x) {
    unsigned int u = __float_as_uint(x);
    unsigned int r = u + 0x7fffu + ((u >> 16) & 1u);
    return (unsigned short)(r >> 16);
}

// permuted fragment element index within a 64-row chunk (16B units):
//   e = ks*128 + rg*64 + khv*32 + col ; row r = rg*32+col holds k = ks*16+khv*8 .. +8
__device__ __forceinline__ int perm_e(int r, int kk) {
    return ((kk >> 4) * 128) + ((r >> 5) * 64) + (((kk >> 3) & 1) * 32) + (r & 31);
}

__device__ __forceinline__ u16x8 pack8(float4 a, float4 b) {
    u16x8 h;
    h[0] = bf16rne(a.x); h[1] = bf16rne(a.y); h[2] = bf16rne(a.z); h[3] = bf16rne(a.w);
    h[4] = bf16rne(b.x); h[5] = bf16rne(b.y); h[6] = bf16rne(b.z); h[7] = bf16rne(b.w);
    return h;
}

__global__ void k_init(int* pos_of, float* accp) {
    int i = blockIdx.x * 256 + threadIdx.x;
    if (i < N_CAND) pos_of[i] = -1;
    if (i == 0) accp[0] = 0.f;
}

__global__ void k_scatter(const int* __restrict__ trg, int* __restrict__ pos_of) {
    int j = threadIdx.x;   // atomicMax => last batch row wins on duplicates
    atomicMax(&pos_of[trg[j]], j);
}

__global__ __launch_bounds__(256) void k_prep(const float* __restrict__ features,
                                              const float* __restrict__ W,
                                              const float* __restrict__ bias,
                                              float* __restrict__ f_norm,
                                              float* __restrict__ softm) {
    int b = blockIdx.x, t = threadIdx.x;
    __shared__ float row[256];
    __shared__ float red[256];
    float x = features[b * D_DIM + t];
    row[t] = x; red[t] = x * x;
    __syncthreads();
    for (int s = 128; s > 0; s >>= 1) {
        if (t < s) red[t] += red[t + s];
        __syncthreads();
    }
    float nrm = fmaxf(sqrtf(red[0]), 1e-12f);
    f_norm[b * D_DIM + t] = x / nrm;
    if (t < C_DIM) {
        float acc = bias[t];
        for (int d = 0; d < D_DIM; ++d) acc = fmaf(row[d], W[d * C_DIM + t], acc);
        float mx = acc;
        for (int off = 32; off > 0; off >>= 1) mx = fmaxf(mx, __shfl_xor(mx, off, 64));
        float e = expf(acc - mx);
        float ssum = e;
        for (int off = 32; off > 0; off >>= 1) ssum += __shfl_xor(ssum, off, 64);
        softm[b * C_DIM + t] = e / ssum;
    }
}

// one-shot: fea_bank (with f_norm substitution) -> pre-permuted bf16 chunks
__global__ __launch_bounds__(256) void k_convert(const float* __restrict__ fea_bank,
                                                 const float* __restrict__ f_norm,
                                                 const int* __restrict__ pos_of,
                                                 short* __restrict__ bank) {
    int cc = blockIdx.x, t = threadIdx.x;
    int r = t >> 2, q4 = t & 3;
    int n = cc * CHUNK + r;
    int p = pos_of[n];
    const float* src = (p >= 0) ? (f_norm + (size_t)p * D_DIM)
                                : (fea_bank + (size_t)n * D_DIM);
    short* dst = bank + (size_t)cc * CHUNK_SH;
    #pragma unroll
    for (int i = 0; i < 8; ++i) {
        int kk = q4 * 64 + i * 8;
        float4 a = *(const float4*)(src + kk);
        float4 b = *(const float4*)(src + kk + 4);
        *(u16x8*)(dst + (size_t)perm_e(r, kk) * 8) = pack8(a, b);
    }
}

// permute query rows (optionally gathered via idx + pos_of substitution) into bf16 tiles
__global__ __launch_bounds__(256) void k_permq(const float* __restrict__ rows,
                                               const float* __restrict__ fea_bank,
                                               const int* __restrict__ idx,
                                               const int* __restrict__ pos_of,
                                               short* __restrict__ dst) {
    int tile = blockIdx.x, t = threadIdx.x;
    int r = t >> 2, q4 = t & 3;
    const float* src;
    if (idx) {
        int n = idx[tile * 64 + r];
        int p = pos_of[n];
        src = (p >= 0) ? (rows + (size_t)p * D_DIM) : (fea_bank + (size_t)n * D_DIM);
    } else {
        src = rows + (size_t)(tile * 64 + r) * D_DIM;
    }
    short* d = dst + (size_t)tile * CHUNK_SH;
    #pragma unroll
    for (int i = 0; i < 8; ++i) {
        int kk = q4 * 64 + i * 8;
        float4 a = *(const float4*)(src + kk);
        float4 b = *(const float4*)(src + kk + 4);
        *(u16x8*)(d + (size_t)perm_e(r, kk) * 8) = pack8(a, b);
    }
}

// MFMA distance + fused per-(query,job) top-6.
// 4 waves, 256 queries/block (64/wave: 32 B-frags, persistent).
// Counted-vmcnt double-buffer pipeline (T3/T4): prefetch loads stay in flight
// across barriers; vmcnt(8) waits only the OLDEST 8 loads (= current chunk).
__global__ __launch_bounds__(256, 2) void dist_topk(const short* __restrict__ qbf,
                                                    const short* __restrict__ bank,
                                                    float* __restrict__ pval,
                                                    int* __restrict__ pidx,
                                                    int nqt, int swz,
                                                    int S, int nchj) {
    __shared__ __align__(16) short sbuf[2 * CHUNK_SH];   // 64 KB double buffer

    int slab, qt;
    if (swz) {
        int bid = blockIdx.x;
        int xcd = bid & 7;
        int rem = bid >> 3;
        qt = rem % nqt;
        slab = (rem / nqt) * 8 + xcd;
        if (slab >= S) return;
    } else {
        slab = blockIdx.x;
        qt = blockIdx.y;
    }
    const int cfirst = slab * nchj;
    int nch = NCHGLB - cfirst; if (nch > nchj) nch = nchj;

    const int t   = threadIdx.x;
    const int w   = t >> 6;
    const int l   = t & 63;
    const int khv = l >> 5;
    const int col = l & 31;

    // ---- B-frags: this wave's 64 queries (2 groups of 32), full K in registers ----
    const short* qtile = qbf + (size_t)(qt * 4 + w) * CHUNK_SH;
    bf16x8 bfr0[16], bfr1[16];
    #pragma unroll
    for (int ks = 0; ks < 16; ++ks) {
        bfr0[ks] = *(const bf16x8*)(qtile + (size_t)(ks * 128      + l) * 8);
        bfr1[ks] = *(const bf16x8*)(qtile + (size_t)(ks * 128 + 64 + l) * 8);
    }

    float lv0[6], lv1[6]; int li0[6], li1[6];
    #pragma unroll
    for (int k = 0; k < 6; ++k) {
        lv0[k] = -3.4e38f; li0[k] = 0x7fffffff;
        lv1[k] = -3.4e38f; li1[k] = 0x7fffffff;
    }

    const short* sbase = bank + (size_t)cfirst * CHUNK_SH;

    // ---- prologue: issue loads(0) into buf 0 ----
    #pragma unroll
    for (int i = 0; i < 8; ++i) {
        const short* gp = sbase + (size_t)(i * 256 + t) * 8;
        short* lp = sbuf + (size_t)(i * 256 + w * 64) * 8;
        __builtin_amdgcn_global_load_lds(
            (const __attribute__((address_space(1))) void*)gp,
            (__attribute__((address_space(3))) void*)lp, 16, 0, 0);
    }

    for (int ch = 0; ch < nch; ++ch) {
        const int cur = ch & 1;
        if (ch + 1 < nch) {
            // issue loads(ch+1); buffer was last read in compute(ch-1), and the
            // end-of-compute barrier below guarantees all waves finished it.
            const short* g = sbase + (size_t)(ch + 1) * CHUNK_SH;
            short* lbase = sbuf + (size_t)(cur ^ 1) * CHUNK_SH;
            #pragma unroll
            for (int i = 0; i < 8; ++i) {
                const short* gp = g + (size_t)(i * 256 + t) * 8;
                short* lp = lbase + (size_t)(i * 256 + w * 64) * 8;
                __builtin_amdgcn_global_load_lds(
                    (const __attribute__((address_space(1))) void*)gp,
                    (__attribute__((address_space(3))) void*)lp, 16, 0, 0);
            }
            // wait only the OLDEST 8 (= loads(ch)); keep the 8 just issued in flight
            asm volatile("s_waitcnt vmcnt(8)" ::: "memory");
        } else {
            asm volatile("s_waitcnt vmcnt(0)" ::: "memory");
        }
        __builtin_amdgcn_s_barrier();          // all waves' loads(ch) landed
        __builtin_amdgcn_sched_barrier(0);     // keep ds_reads below the barrier

        const short* cb = sbuf + (size_t)cur * CHUNK_SH;

        #pragma unroll
        for (int half = 0; half < 2; ++half) {
            f32x16 a0 = {}, a1 = {};
            #pragma unroll
            for (int ks = 0; ks < 16; ++ks) {
                bf16x8 fa = *(const bf16x8*)(cb + (size_t)(ks * 128 + half * 64 + l) * 8);
                a0 = __builtin_amdgcn_mfma_f32_32x32x16_bf16(fa, bfr0[ks], a0, 0, 0, 0);
                a1 = __builtin_amdgcn_mfma_f32_32x32x16_bf16(fa, bfr1[ks], a1, 0, 0, 0);
            }

            const int cb0 = (cfirst + ch) * CHUNK + half * 32;

            {   // query-group 0
                float mx = a0[0];
                #pragma unroll
                for (int r = 1; r < 16; ++r) mx = fmaxf(mx, a0[r]);
                if (mx >= lv0[5]) {
                    #pragma unroll
                    for (int r = 0; r < 16; ++r) {
                        int m = (r & 3) + 8 * (r >> 2) + 4 * khv;
                        insert6(lv0, li0, a0[r], cb0 + m);
                    }
                }
            }
            {   // query-group 1
                float mx = a1[0];
                #pragma unroll
                for (int r = 1; r < 16; ++r) mx = fmaxf(mx, a1[r]);
                if (mx >= lv1[5]) {
                    #pragma unroll
                    for (int r = 0; r < 16; ++r) {
                        int m = (r & 3) + 8 * (r >> 2) + 4 * khv;
                        insert6(lv1, li1, a1[r], cb0 + m);
                    }
                }
            }
        }

        __builtin_amdgcn_sched_barrier(0);     // keep next iter's loads above-barrier-free
        __builtin_amdgcn_s_barrier();          // all waves done reading buf[cur]
    }

    // ---- per-job merge: 2 lanes (khv) per query, 256 queries ----
    __syncthreads();
    float* mlv = (float*)sbuf;                          // [256][2][6] floats (12KB)
    int*   mli = (int*)(sbuf + CHUNK_SH);               // [256][2][6] ints
    int q0 = w * 64 + col;
    int q1 = w * 64 + 32 + col;
    #pragma unroll
    for (int k = 0; k < 6; ++k) {
        mlv[(q0 * 2 + khv) * 6 + k] = lv0[k];
        mli[(q0 * 2 + khv) * 6 + k] = li0[k];
        mlv[(q1 * 2 + khv) * 6 + k] = lv1[k];
        mli[(q1 * 2 + khv) * 6 + k] = li1[k];
    }
    __syncthreads();
    {
        float fv[6]; int fi[6];
        #pragma unroll
        for (int k = 0; k < 6; ++k) { fv[k] = -3.4e38f; fi[k] = 0x7fffffff; }
        for (int s = 0; s < 2; ++s)
            #pragma unroll
            for (int k = 0; k < 6; ++k)
                insert6(fv, fi, mlv[(t * 2 + s) * 6 + k], mli[(t * 2 + s) * 6 + k]);
        size_t base = ((size_t)(qt * 256 + t) * S + slab) * 6;
        #pragma unroll
        for (int k = 0; k < 6; ++k) { pval[base + k] = fv[k]; pidx[base + k] = fi[k]; }
    }
}

__global__ __launch_bounds__(256) void topk_merge(const float* __restrict__ pval,
                                                  const int* __restrict__ pidx,
                                                  int* __restrict__ out_idx,
                                                  int S) {
    int q = blockIdx.x, t = threadIdx.x;
    const int total = S * 6;
    float lv[6]; int li[6];
    #pragma unroll
    for (int k = 0; k < 6; ++k) { lv[k] = -3.4e38f; li[k] = 0x7fffffff; }
    size_t base = (size_t)q * total;
    for (int e = t; e < total; e += 256) insert6(lv, li, pval[base + e], pidx[base + e]);
    __shared__ float sv[256][6];
    __shared__ int   si[256][6];
    #pragma unroll
    for (int k = 0; k < 6; ++k) { sv[t][k] = lv[k]; si[t][k] = li[k]; }
    __syncthreads();
    for (int w = 128; w >= 1; w >>= 1) {
        if (t < w) {
            float ov[6]; int oi[6];
            merge6(sv[t], si[t], sv[t + w], si[t + w], ov, oi);
            #pragma unroll
            for (int k = 0; k < 6; ++k) { sv[t][k] = ov[k]; si[t][k] = oi[k]; }
        }
        __syncthreads();
    }
    if (t == 0) {
        for (int k = 1; k < 6; ++k) out_idx[q * K_TOP + k - 1] = si[0][k];
    }
}

__global__ void k_loss(const float* __restrict__ softm, const float* __restrict__ score_bank,
                       const int* __restrict__ pos_of, const int* __restrict__ idx_near,
                       const int* __restrict__ idx_nn, const int* __restrict__ trg,
                       float* accp) {
    int b = blockIdx.x, c = threadIdx.x;   // 64 threads
    float p_bc = softm[b * C_DIM + c];
    float part = 0.f;
    for (int k = 0; k < K_TOP; ++k) {
        for (int j = 0; j < K_TOP; ++j) {
            int n = idx_nn[(b * K_TOP + k) * K_TOP + j];
            int p = pos_of[n];
            const float* srow = (p >= 0) ? (softm + (size_t)p * C_DIM)
                                         : (score_bank + (size_t)n * C_DIM);
            float s = srow[c];
            float v = s * (logf(s) - p_bc);
            for (int off = 32; off > 0; off >>= 1) v += __shfl_down(v, off, 64);
            if (c == 0) part += 0.1f * v;
        }
    }
    for (int k = 0; k < K_TOP; ++k) {
        int n = idx_near[b * K_TOP + k];
        int p = pos_of[n];
        const float* srow = (p >= 0) ? (softm + (size_t)p * C_DIM)
                                     : (score_bank + (size_t)n * C_DIM);
        float s = srow[c];
        float v = s * (logf(s) - p_bc);
        for (int off = 32; off > 0; off >>= 1) v += __shfl_down(v, off, 64);
        if (c == 0) {
            int m = 0;
            for (int j = 0; j < K_TOP; ++j)
                m += (idx_nn[(b * K_TOP + k) * K_TOP + j] == trg[b]) ? 1 : 0;
            float w = (m > 0) ? (float)m : 0.1f;
            part += w * v;
        }
    }
    if (c == 0) atomicAdd(accp, part * (1.0f / (float)B_SZ));
}

__global__ void k_final(const float* __restrict__ softm, const float* __restrict__ accp,
                        float* __restrict__ out) {
    int c = threadIdx.x;   // 64
    float m = 0.f;
    for (int b = 0; b < B_SZ; ++b) m += softm[b * C_DIM + c];
    m *= (1.0f / (float)B_SZ);
    float g = m * logf(m + 1e-5f);
    for (int off = 32; off > 0; off >>= 1) g += __shfl_down(g, off, 64);
    if (c == 0) out[0] = accp[0] + g;
}

extern "C" void kernel_launch(void* const* d_in, const int* in_sizes, int n_in,
                              void* d_out, int out_size, void* d_ws, size_t ws_size,
                              hipStream_t stream) {
    const float* features   = (const float*)d_in[0];
    const float* W          = (const float*)d_in[1];
    const float* bias       = (const float*)d_in[2];
    const float* fea_bank   = (const float*)d_in[3];
    const float* score_bank = (const float*)d_in[4];
    const int*   trg        = (const int*)d_in[5];
    float* out = (float*)d_out;

    char* ws = (char*)d_ws;
    size_t off = 0;
    auto alloc = [&](size_t bytes) -> void* {
        void* p = ws + off;
        off = (off + bytes + 255) & ~(size_t)255;
        return p;
    };
    short* bankbf   = (short*)alloc((size_t)NCHGLB * CHUNK_SH * 2);         // 102.4 MB
    short* q1bf     = (short*)alloc((size_t)(B_SZ / 64) * CHUNK_SH * 2);    // 256 KB
    short* q2bf     = (short*)alloc((size_t)(B_SZ * K_TOP / 64) * CHUNK_SH * 2); // 640 KB
    float* f_norm   = (float*)alloc((size_t)B_SZ * D_DIM * 4);
    float* softm    = (float*)alloc((size_t)B_SZ * C_DIM * 4);
    int*   pos_of   = (int*)alloc((size_t)N_CAND * 4);
    float* accp     = (float*)alloc(4);
    int*   idx_near = (int*)alloc((size_t)B_SZ * K_TOP * 4);
    int*   idx_nn   = (int*)alloc((size_t)B_SZ * K_TOP * K_TOP * 4);
    float* pv1      = (float*)alloc((size_t)B_SZ * S1 * 6 * 4);
    int*   pi1      = (int*)alloc((size_t)B_SZ * S1 * 6 * 4);
    float* pv2      = (float*)alloc((size_t)B_SZ * K_TOP * S2 * 6 * 4);
    int*   pi2      = (int*)alloc((size_t)B_SZ * K_TOP * S2 * 6 * 4);

    k_init<<<dim3((N_CAND + 255) / 256), dim3(256), 0, stream>>>(pos_of, accp);
    k_scatter<<<dim3(1), dim3(256), 0, stream>>>(trg, pos_of);
    k_prep<<<dim3(B_SZ), dim3(256), 0, stream>>>(features, W, bias, f_norm, softm);

    // one-shot bank convert (substituted, permuted, bf16)
    k_convert<<<dim3(NCHGLB), dim3(256), 0, stream>>>(fea_bank, f_norm, pos_of, bankbf);
    // pass-1 query tiles from f_norm (4 x 64-query tiles = 256 queries)
    k_permq<<<dim3(B_SZ / 64), dim3(256), 0, stream>>>(f_norm, fea_bank, nullptr, pos_of, q1bf);

    // pass 1: 256 queries = 1 block-qtile; 8-chunk jobs -> 391 blocks (fills 256 CUs)
    dist_topk<<<dim3(S1, 1), dim3(256), 0, stream>>>(
        q1bf, bankbf, pv1, pi1, 1, 0, S1, NCHJ1);
    topk_merge<<<dim3(B_SZ), dim3(256), 0, stream>>>(pv1, pi1, idx_near, S1);

    // pass-2 query tiles: gather idx_near rows (substituted) -> permuted bf16
    k_permq<<<dim3(B_SZ * K_TOP / 64), dim3(256), 0, stream>>>(
        f_norm, fea_bank, idx_near, pos_of, q2bf);

    // pass 2: 1280 queries = 5 block-qtiles, 16-chunk jobs, XCD-grouped mapping
    {
        int nqt = (B_SZ * K_TOP) / 256;           // 5
        int nsg = (S2 + 7) / 8;                   // 25
        dist_topk<<<dim3(nsg * 8 * nqt), dim3(256), 0, stream>>>(
            q2bf, bankbf, pv2, pi2, nqt, 1, S2, NCHJ2);
    }
    topk_merge<<<dim3(B_SZ * K_TOP), dim3(256), 0, stream>>>(pv2, pi2, idx_nn, S2);

    k_loss<<<dim3(B_SZ), dim3(64), 0, stream>>>(softm, score_bank, pos_of, idx_near, idx_nn, trg, accp);
    k_final<<<dim3(1), dim3(64), 0, stream>>>(softm, accp, out);
}

// Round 11
// 342.092 us; speedup vs baseline: 2.0259x; 2.0259x over previous
//
#include <hip/hip_runtime.h>
#include <hip/hip_bf16.h>
#include <math.h>

#define B_SZ   256
#define D_DIM  256
#define C_DIM  64
#define N_CAND 200000
#define K_TOP  5
#define CHUNK  64
#define NCHGLB (N_CAND / CHUNK)               // 3125 bank chunks (exact)
#define CHUNK_SH 16384                        // shorts per permuted 64-row chunk (32KB)
#define NCHJ1  8                              // chunks per job, pass 1 (pos fits 8*32=256 < 512)
#define NCHJ2  16                             // chunks per job, pass 2 (pos fits 16*32=512)
#define S1     ((NCHGLB + NCHJ1 - 1) / NCHJ1) // 391 jobs
#define S2     ((NCHGLB + NCHJ2 - 1) / NCHJ2) // 196 jobs

typedef short bf16x8 __attribute__((ext_vector_type(8)));
typedef float f32x16 __attribute__((ext_vector_type(16)));
typedef unsigned short u16x8 __attribute__((ext_vector_type(8)));

__device__ __forceinline__ bool better(float v1, int i1, float v2, int i2) {
    return (v1 > v2) || (v1 == v2 && i1 < i2);
}

// merge-path insert used only in topk_merge (off hot path)
__device__ __forceinline__ void insert6f(float* lv, int* li, float v, int idx) {
    if (better(v, idx, lv[5], li[5])) {
        lv[5] = v; li[5] = idx;
        #pragma unroll
        for (int k = 5; k > 0; --k) {
            if (better(lv[k], li[k], lv[k - 1], li[k - 1])) {
                float tv = lv[k]; lv[k] = lv[k - 1]; lv[k - 1] = tv;
                int   ti = li[k]; li[k] = li[k - 1]; li[k - 1] = ti;
            }
        }
    }
}

__device__ __forceinline__ void merge6(const float* av, const int* ai,
                                       const float* bv, const int* bi,
                                       float* ov, int* oi) {
    int ia = 0, ib = 0;
    #pragma unroll
    for (int k = 0; k < 6; ++k) {
        bool ta;
        if (ia >= 6)      ta = false;
        else if (ib >= 6) ta = true;
        else              ta = better(av[ia], ai[ia], bv[ib], bi[ib]);
        if (ta) { ov[k] = av[ia]; oi[k] = ai[ia]; ++ia; }
        else    { ov[k] = bv[ib]; oi[k] = bi[ib]; ++ib; }
    }
}

__device__ __forceinline__ unsigned med3u(unsigned a, unsigned b, unsigned c) {
    unsigned d;
    asm("v_med3_u32 %0, %1, %2, %3" : "=v"(d) : "v"(a), "v"(b), "v"(c));
    return d;
}

// exact sorted-desc top-6 insert, depth-1: kv sorted desc (kv[0] largest).
// n0 = max(x,kv0); ni = median(x, kv[i-1], kv[i]) — all from OLD values.
__device__ __forceinline__ void kinsert(unsigned* kv, unsigned x) {
    unsigned n0 = kv[0] > x ? kv[0] : x;
    unsigned n1 = med3u(x, kv[0], kv[1]);
    unsigned n2 = med3u(x, kv[1], kv[2]);
    unsigned n3 = med3u(x, kv[2], kv[3]);
    unsigned n4 = med3u(x, kv[3], kv[4]);
    unsigned n5 = med3u(x, kv[4], kv[5]);
    kv[0] = n0; kv[1] = n1; kv[2] = n2; kv[3] = n3; kv[4] = n4; kv[5] = n5;
}

__device__ __forceinline__ unsigned short bf16rne(float x) {
    unsigned int u = __float_as_uint(x);
    unsigned int r = u + 0x7fffu + ((u >> 16) & 1u);
    return (unsigned short)(r >> 16);
}

// permuted fragment element index within a 64-row chunk (16B units)
__device__ __forceinline__ int perm_e(int r, int kk) {
    return ((kk >> 4) * 128) + ((r >> 5) * 64) + (((kk >> 3) & 1) * 32) + (r & 31);
}

__device__ __forceinline__ u16x8 pack8(float4 a, float4 b) {
    u16x8 h;
    h[0] = bf16rne(a.x); h[1] = bf16rne(a.y); h[2] = bf16rne(a.z); h[3] = bf16rne(a.w);
    h[4] = bf16rne(b.x); h[5] = bf16rne(b.y); h[6] = bf16rne(b.z); h[7] = bf16rne(b.w);
    return h;
}

__global__ void k_init(int* pos_of, float* accp) {
    int i = blockIdx.x * 256 + threadIdx.x;
    if (i < N_CAND) pos_of[i] = -1;
    if (i == 0) accp[0] = 0.f;
}

__global__ void k_scatter(const int* __restrict__ trg, int* __restrict__ pos_of) {
    int j = threadIdx.x;
    atomicMax(&pos_of[trg[j]], j);
}

__global__ __launch_bounds__(256) void k_prep(const float* __restrict__ features,
                                              const float* __restrict__ W,
                                              const float* __restrict__ bias,
                                              float* __restrict__ f_norm,
                                              float* __restrict__ softm) {
    int b = blockIdx.x, t = threadIdx.x;
    __shared__ float row[256];
    __shared__ float red[256];
    float x = features[b * D_DIM + t];
    row[t] = x; red[t] = x * x;
    __syncthreads();
    for (int s = 128; s > 0; s >>= 1) {
        if (t < s) red[t] += red[t + s];
        __syncthreads();
    }
    float nrm = fmaxf(sqrtf(red[0]), 1e-12f);
    f_norm[b * D_DIM + t] = x / nrm;
    if (t < C_DIM) {
        float acc = bias[t];
        for (int d = 0; d < D_DIM; ++d) acc = fmaf(row[d], W[d * C_DIM + t], acc);
        float mx = acc;
        for (int off = 32; off > 0; off >>= 1) mx = fmaxf(mx, __shfl_xor(mx, off, 64));
        float e = expf(acc - mx);
        float ssum = e;
        for (int off = 32; off > 0; off >>= 1) ssum += __shfl_xor(ssum, off, 64);
        softm[b * C_DIM + t] = e / ssum;
    }
}

__global__ __launch_bounds__(256) void k_convert(const float* __restrict__ fea_bank,
                                                 const float* __restrict__ f_norm,
                                                 const int* __restrict__ pos_of,
                                                 short* __restrict__ bank) {
    int cc = blockIdx.x, t = threadIdx.x;
    int r = t >> 2, q4 = t & 3;
    int n = cc * CHUNK + r;
    int p = pos_of[n];
    const float* src = (p >= 0) ? (f_norm + (size_t)p * D_DIM)
                                : (fea_bank + (size_t)n * D_DIM);
    short* dst = bank + (size_t)cc * CHUNK_SH;
    #pragma unroll
    for (int i = 0; i < 8; ++i) {
        int kk = q4 * 64 + i * 8;
        float4 a = *(const float4*)(src + kk);
        float4 b = *(const float4*)(src + kk + 4);
        *(u16x8*)(dst + (size_t)perm_e(r, kk) * 8) = pack8(a, b);
    }
}

__global__ __launch_bounds__(256) void k_permq(const float* __restrict__ rows,
                                               const float* __restrict__ fea_bank,
                                               const int* __restrict__ idx,
                                               const int* __restrict__ pos_of,
                                               short* __restrict__ dst) {
    int tile = blockIdx.x, t = threadIdx.x;
    int r = t >> 2, q4 = t & 3;
    const float* src;
    if (idx) {
        int n = idx[tile * 64 + r];
        int p = pos_of[n];
        src = (p >= 0) ? (rows + (size_t)p * D_DIM) : (fea_bank + (size_t)n * D_DIM);
    } else {
        src = rows + (size_t)(tile * 64 + r) * D_DIM;
    }
    short* d = dst + (size_t)tile * CHUNK_SH;
    #pragma unroll
    for (int i = 0; i < 8; ++i) {
        int kk = q4 * 64 + i * 8;
        float4 a = *(const float4*)(src + kk);
        float4 b = *(const float4*)(src + kk + 4);
        *(u16x8*)(d + (size_t)perm_e(r, kk) * 8) = pack8(a, b);
    }
}

// MFMA distance + fused top-6 via packed u32 keys.
// acc init = 2.0f => dot+2 in [1,3] (positive) => IEEE bits are order-preserving.
// key = (bits & ~0x1FF) | (511 - pos); pos = ch*32 + half*16 + r (job-local).
// Top-6 kept with 1 vmax + 5 med3_u32 per value, unconditional, depth-1.
__global__ __launch_bounds__(256, 2) void dist_topk(const short* __restrict__ qbf,
                                                    const short* __restrict__ bank,
                                                    float* __restrict__ pval,
                                                    int* __restrict__ pidx,
                                                    int nqt, int swz,
                                                    int S, int nchj) {
    __shared__ __align__(16) short sbuf[2 * CHUNK_SH];   // 64 KB double buffer

    int slab, qt;
    if (swz) {
        int bid = blockIdx.x;
        int xcd = bid & 7;
        int rem = bid >> 3;
        qt = rem % nqt;
        slab = (rem / nqt) * 8 + xcd;
        if (slab >= S) return;
    } else {
        slab = blockIdx.x;
        qt = blockIdx.y;
    }
    const int cfirst = slab * nchj;
    int nch = NCHGLB - cfirst; if (nch > nchj) nch = nchj;

    const int t   = threadIdx.x;
    const int w   = t >> 6;
    const int l   = t & 63;
    const int khv = l >> 5;
    const int col = l & 31;

    // ---- B-frags: this wave's 64 queries (2 groups of 32), full K in registers ----
    const short* qtile = qbf + (size_t)(qt * 4 + w) * CHUNK_SH;
    bf16x8 bfr0[16], bfr1[16];
    #pragma unroll
    for (int ks = 0; ks < 16; ++ks) {
        bfr0[ks] = *(const bf16x8*)(qtile + (size_t)(ks * 128      + l) * 8);
        bfr1[ks] = *(const bf16x8*)(qtile + (size_t)(ks * 128 + 64 + l) * 8);
    }

    unsigned kv0[6], kv1[6];
    #pragma unroll
    for (int k = 0; k < 6; ++k) { kv0[k] = 0u; kv1[k] = 0u; }

    const short* sbase = bank + (size_t)cfirst * CHUNK_SH;

    // ---- prologue: issue loads(0) into buf 0 ----
    #pragma unroll
    for (int i = 0; i < 8; ++i) {
        const short* gp = sbase + (size_t)(i * 256 + t) * 8;
        short* lp = sbuf + (size_t)(i * 256 + w * 64) * 8;
        __builtin_amdgcn_global_load_lds(
            (const __attribute__((address_space(1))) void*)gp,
            (__attribute__((address_space(3))) void*)lp, 16, 0, 0);
    }

    for (int ch = 0; ch < nch; ++ch) {
        const int cur = ch & 1;
        if (ch + 1 < nch) {
            const short* g = sbase + (size_t)(ch + 1) * CHUNK_SH;
            short* lbase = sbuf + (size_t)(cur ^ 1) * CHUNK_SH;
            #pragma unroll
            for (int i = 0; i < 8; ++i) {
                const short* gp = g + (size_t)(i * 256 + t) * 8;
                short* lp = lbase + (size_t)(i * 256 + w * 64) * 8;
                __builtin_amdgcn_global_load_lds(
                    (const __attribute__((address_space(1))) void*)gp,
                    (__attribute__((address_space(3))) void*)lp, 16, 0, 0);
            }
            asm volatile("s_waitcnt vmcnt(8)" ::: "memory");
        } else {
            asm volatile("s_waitcnt vmcnt(0)" ::: "memory");
        }
        __builtin_amdgcn_s_barrier();
        __builtin_amdgcn_sched_barrier(0);

        const short* cb = sbuf + (size_t)cur * CHUNK_SH;

        #pragma unroll
        for (int half = 0; half < 2; ++half) {
            f32x16 a0, a1;
            #pragma unroll
            for (int i = 0; i < 16; ++i) { a0[i] = 2.0f; a1[i] = 2.0f; }
            #pragma unroll
            for (int ks = 0; ks < 16; ++ks) {
                bf16x8 fa = *(const bf16x8*)(cb + (size_t)(ks * 128 + half * 64 + l) * 8);
                a0 = __builtin_amdgcn_mfma_f32_32x32x16_bf16(fa, bfr0[ks], a0, 0, 0, 0);
                a1 = __builtin_amdgcn_mfma_f32_32x32x16_bf16(fa, bfr1[ks], a1, 0, 0, 0);
            }

            const unsigned invb = 511u - (unsigned)(ch * 32 + half * 16);
            #pragma unroll
            for (int r = 0; r < 16; ++r) {
                unsigned x0 = (__float_as_uint(a0[r]) & 0xFFFFFE00u) | (invb - r);
                unsigned x1 = (__float_as_uint(a1[r]) & 0xFFFFFE00u) | (invb - r);
                kinsert(kv0, x0);
                kinsert(kv1, x1);
            }
        }

        __builtin_amdgcn_sched_barrier(0);
        __builtin_amdgcn_s_barrier();
    }

    // ---- decode + direct global write (no LDS merge): 2 lists per thread ----
    {
        int q0 = qt * 256 + w * 64 + col;
        int q1 = qt * 256 + w * 64 + 32 + col;
        size_t b0 = ((size_t)q0 * S + slab) * 12 + khv * 6;
        size_t b1 = ((size_t)q1 * S + slab) * 12 + khv * 6;
        #pragma unroll
        for (int k = 0; k < 6; ++k) {
            unsigned key0 = kv0[k], key1 = kv1[k];
            int pos0 = 511 - (int)(key0 & 511u);
            int pos1 = 511 - (int)(key1 & 511u);
            int r0 = pos0 & 15, h0 = (pos0 >> 4) & 1, c0 = pos0 >> 5;
            int r1 = pos1 & 15, h1 = (pos1 >> 4) & 1, c1 = pos1 >> 5;
            int m0 = (r0 & 3) + 8 * (r0 >> 2) + 4 * khv;
            int m1 = (r1 & 3) + 8 * (r1 >> 2) + 4 * khv;
            pval[b0 + k] = __uint_as_float(key0 & 0xFFFFFE00u);
            pidx[b0 + k] = (cfirst + c0) * CHUNK + h0 * 32 + m0;
            pval[b1 + k] = __uint_as_float(key1 & 0xFFFFFE00u);
            pidx[b1 + k] = (cfirst + c1) * CHUNK + h1 * 32 + m1;
        }
    }
}

__global__ __launch_bounds__(256) void topk_merge(const float* __restrict__ pval,
                                                  const int* __restrict__ pidx,
                                                  int* __restrict__ out_idx,
                                                  int S) {
    int q = blockIdx.x, t = threadIdx.x;
    const int total = S * 12;
    float lv[6]; int li[6];
    #pragma unroll
    for (int k = 0; k < 6; ++k) { lv[k] = -3.4e38f; li[k] = 0x7fffffff; }
    size_t base = (size_t)q * total;
    for (int e = t; e < total; e += 256) insert6f(lv, li, pval[base + e], pidx[base + e]);
    __shared__ float sv[256][6];
    __shared__ int   si[256][6];
    #pragma unroll
    for (int k = 0; k < 6; ++k) { sv[t][k] = lv[k]; si[t][k] = li[k]; }
    __syncthreads();
    for (int w = 128; w >= 1; w >>= 1) {
        if (t < w) {
            float ov[6]; int oi[6];
            merge6(sv[t], si[t], sv[t + w], si[t + w], ov, oi);
            #pragma unroll
            for (int k = 0; k < 6; ++k) { sv[t][k] = ov[k]; si[t][k] = oi[k]; }
        }
        __syncthreads();
    }
    if (t == 0) {
        for (int k = 1; k < 6; ++k) out_idx[q * K_TOP + k - 1] = si[0][k];
    }
}

__global__ void k_loss(const float* __restrict__ softm, const float* __restrict__ score_bank,
                       const int* __restrict__ pos_of, const int* __restrict__ idx_near,
                       const int* __restrict__ idx_nn, const int* __restrict__ trg,
                       float* accp) {
    int b = blockIdx.x, c = threadIdx.x;   // 64 threads
    float p_bc = softm[b * C_DIM + c];
    float part = 0.f;
    for (int k = 0; k < K_TOP; ++k) {
        for (int j = 0; j < K_TOP; ++j) {
            int n = idx_nn[(b * K_TOP + k) * K_TOP + j];
            int p = pos_of[n];
            const float* srow = (p >= 0) ? (softm + (size_t)p * C_DIM)
                                         : (score_bank + (size_t)n * C_DIM);
            float s = srow[c];
            float v = s * (logf(s) - p_bc);
            for (int off = 32; off > 0; off >>= 1) v += __shfl_down(v, off, 64);
            if (c == 0) part += 0.1f * v;
        }
    }
    for (int k = 0; k < K_TOP; ++k) {
        int n = idx_near[b * K_TOP + k];
        int p = pos_of[n];
        const float* srow = (p >= 0) ? (softm + (size_t)p * C_DIM)
                                     : (score_bank + (size_t)n * C_DIM);
        float s = srow[c];
        float v = s * (logf(s) - p_bc);
        for (int off = 32; off > 0; off >>= 1) v += __shfl_down(v, off, 64);
        if (c == 0) {
            int m = 0;
            for (int j = 0; j < K_TOP; ++j)
                m += (idx_nn[(b * K_TOP + k) * K_TOP + j] == trg[b]) ? 1 : 0;
            float w = (m > 0) ? (float)m : 0.1f;
            part += w * v;
        }
    }
    if (c == 0) atomicAdd(accp, part * (1.0f / (float)B_SZ));
}

__global__ void k_final(const float* __restrict__ softm, const float* __restrict__ accp,
                        float* __restrict__ out) {
    int c = threadIdx.x;   // 64
    float m = 0.f;
    for (int b = 0; b < B_SZ; ++b) m += softm[b * C_DIM + c];
    m *= (1.0f / (float)B_SZ);
    float g = m * logf(m + 1e-5f);
    for (int off = 32; off > 0; off >>= 1) g += __shfl_down(g, off, 64);
    if (c == 0) out[0] = accp[0] + g;
}

extern "C" void kernel_launch(void* const* d_in, const int* in_sizes, int n_in,
                              void* d_out, int out_size, void* d_ws, size_t ws_size,
                              hipStream_t stream) {
    const float* features   = (const float*)d_in[0];
    const float* W          = (const float*)d_in[1];
    const float* bias       = (const float*)d_in[2];
    const float* fea_bank   = (const float*)d_in[3];
    const float* score_bank = (const float*)d_in[4];
    const int*   trg        = (const int*)d_in[5];
    float* out = (float*)d_out;

    char* ws = (char*)d_ws;
    size_t off = 0;
    auto alloc = [&](size_t bytes) -> void* {
        void* p = ws + off;
        off = (off + bytes + 255) & ~(size_t)255;
        return p;
    };
    short* bankbf   = (short*)alloc((size_t)NCHGLB * CHUNK_SH * 2);         // 102.4 MB
    short* q1bf     = (short*)alloc((size_t)(B_SZ / 64) * CHUNK_SH * 2);
    short* q2bf     = (short*)alloc((size_t)(B_SZ * K_TOP / 64) * CHUNK_SH * 2);
    float* f_norm   = (float*)alloc((size_t)B_SZ * D_DIM * 4);
    float* softm    = (float*)alloc((size_t)B_SZ * C_DIM * 4);
    int*   pos_of   = (int*)alloc((size_t)N_CAND * 4);
    float* accp     = (float*)alloc(4);
    int*   idx_near = (int*)alloc((size_t)B_SZ * K_TOP * 4);
    int*   idx_nn   = (int*)alloc((size_t)B_SZ * K_TOP * K_TOP * 4);
    float* pv1      = (float*)alloc((size_t)B_SZ * S1 * 12 * 4);
    int*   pi1      = (int*)alloc((size_t)B_SZ * S1 * 12 * 4);
    float* pv2      = (float*)alloc((size_t)B_SZ * K_TOP * S2 * 12 * 4);
    int*   pi2      = (int*)alloc((size_t)B_SZ * K_TOP * S2 * 12 * 4);

    k_init<<<dim3((N_CAND + 255) / 256), dim3(256), 0, stream>>>(pos_of, accp);
    k_scatter<<<dim3(1), dim3(256), 0, stream>>>(trg, pos_of);
    k_prep<<<dim3(B_SZ), dim3(256), 0, stream>>>(features, W, bias, f_norm, softm);

    k_convert<<<dim3(NCHGLB), dim3(256), 0, stream>>>(fea_bank, f_norm, pos_of, bankbf);
    k_permq<<<dim3(B_SZ / 64), dim3(256), 0, stream>>>(f_norm, fea_bank, nullptr, pos_of, q1bf);

    // pass 1: 256 queries = 1 block-qtile; 8-chunk jobs
    dist_topk<<<dim3(S1, 1), dim3(256), 0, stream>>>(
        q1bf, bankbf, pv1, pi1, 1, 0, S1, NCHJ1);
    topk_merge<<<dim3(B_SZ), dim3(256), 0, stream>>>(pv1, pi1, idx_near, S1);

    k_permq<<<dim3(B_SZ * K_TOP / 64), dim3(256), 0, stream>>>(
        f_norm, fea_bank, idx_near, pos_of, q2bf);

    // pass 2: 1280 queries = 5 block-qtiles, 16-chunk jobs, XCD-grouped mapping
    {
        int nqt = (B_SZ * K_TOP) / 256;           // 5
        int nsg = (S2 + 7) / 8;                   // 25
        dist_topk<<<dim3(nsg * 8 * nqt), dim3(256), 0, stream>>>(
            q2bf, bankbf, pv2, pi2, nqt, 1, S2, NCHJ2);
    }
    topk_merge<<<dim3(B_SZ * K_TOP), dim3(256), 0, stream>>>(pv2, pi2, idx_nn, S2);

    k_loss<<<dim3(B_SZ), dim3(64), 0, stream>>>(softm, score_bank, pos_of, idx_near, idx_nn, trg, accp);
    k_final<<<dim3(1), dim3(64), 0, stream>>>(softm, accp, out);
}

// Round 13
// 331.910 us; speedup vs baseline: 2.0881x; 1.0307x over previous
//
#include <hip/hip_runtime.h>
#include <hip/hip_bf16.h>
#include <math.h>

#define B_SZ   256
#define D_DIM  256
#define C_DIM  64
#define N_CAND 200000
#define K_TOP  5
#define CH32   32
#define CH32_SH 8192                          // shorts per 32-cand chunk (16KB)
#define QTILE_SH 16384                        // shorts per 64-query tile (32KB)
#define NCH32  (N_CAND / CH32)                // 6250 chunks (exact)
#define NCHJ1  16                             // chunks/job pass 1 (pos < 512)
#define NCHJ2  32                             // chunks/job pass 2 (pos < 1024)
#define S1     ((NCH32 + NCHJ1 - 1) / NCHJ1)  // 391
#define S2     ((NCH32 + NCHJ2 - 1) / NCHJ2)  // 196

typedef short bf16x8 __attribute__((ext_vector_type(8)));
typedef float f32x16 __attribute__((ext_vector_type(16)));
typedef unsigned short u16x8 __attribute__((ext_vector_type(8)));

__device__ __forceinline__ bool better(float v1, int i1, float v2, int i2) {
    return (v1 > v2) || (v1 == v2 && i1 < i2);
}

__device__ __forceinline__ void insert6f(float* lv, int* li, float v, int idx) {
    if (better(v, idx, lv[5], li[5])) {
        lv[5] = v; li[5] = idx;
        #pragma unroll
        for (int k = 5; k > 0; --k) {
            if (better(lv[k], li[k], lv[k - 1], li[k - 1])) {
                float tv = lv[k]; lv[k] = lv[k - 1]; lv[k - 1] = tv;
                int   ti = li[k]; li[k] = li[k - 1]; li[k - 1] = ti;
            }
        }
    }
}

__device__ __forceinline__ void merge6(const float* av, const int* ai,
                                       const float* bv, const int* bi,
                                       float* ov, int* oi) {
    int ia = 0, ib = 0;
    #pragma unroll
    for (int k = 0; k < 6; ++k) {
        bool ta;
        if (ia >= 6)      ta = false;
        else if (ib >= 6) ta = true;
        else              ta = better(av[ia], ai[ia], bv[ib], bi[ib]);
        if (ta) { ov[k] = av[ia]; oi[k] = ai[ia]; ++ia; }
        else    { ov[k] = bv[ib]; oi[k] = bi[ib]; ++ib; }
    }
}

__device__ __forceinline__ unsigned med3u(unsigned a, unsigned b, unsigned c) {
    unsigned d;
    asm("v_med3_u32 %0, %1, %2, %3" : "=v"(d) : "v"(a), "v"(b), "v"(c));
    return d;
}

// exact sorted-desc top-6 insert, depth-1 (1 max + 5 med3)
__device__ __forceinline__ void kinsert(unsigned* kv, unsigned x) {
    unsigned n0 = kv[0] > x ? kv[0] : x;
    unsigned n1 = med3u(x, kv[0], kv[1]);
    unsigned n2 = med3u(x, kv[1], kv[2]);
    unsigned n3 = med3u(x, kv[2], kv[3]);
    unsigned n4 = med3u(x, kv[3], kv[4]);
    unsigned n5 = med3u(x, kv[4], kv[5]);
    kv[0] = n0; kv[1] = n1; kv[2] = n2; kv[3] = n3; kv[4] = n4; kv[5] = n5;
}

__device__ __forceinline__ unsigned short bf16rne(float x) {
    unsigned int u = __float_as_uint(x);
    unsigned int r = u + 0x7fffu + ((u >> 16) & 1u);
    return (unsigned short)(r >> 16);
}

__device__ __forceinline__ u16x8 pack8(float4 a, float4 b) {
    u16x8 h;
    h[0] = bf16rne(a.x); h[1] = bf16rne(a.y); h[2] = bf16rne(a.z); h[3] = bf16rne(a.w);
    h[4] = bf16rne(b.x); h[5] = bf16rne(b.y); h[6] = bf16rne(b.z); h[7] = bf16rne(b.w);
    return h;
}

__global__ void k_init(int* pos_of, float* accp) {
    int i = blockIdx.x * 256 + threadIdx.x;
    if (i < N_CAND) pos_of[i] = -1;
    if (i == 0) accp[0] = 0.f;
}

__global__ void k_scatter(const int* __restrict__ trg, int* __restrict__ pos_of) {
    int j = threadIdx.x;
    atomicMax(&pos_of[trg[j]], j);
}

__global__ __launch_bounds__(256) void k_prep(const float* __restrict__ features,
                                              const float* __restrict__ W,
                                              const float* __restrict__ bias,
                                              float* __restrict__ f_norm,
                                              float* __restrict__ softm) {
    int b = blockIdx.x, t = threadIdx.x;
    __shared__ float row[256];
    __shared__ float red[256];
    float x = features[b * D_DIM + t];
    row[t] = x; red[t] = x * x;
    __syncthreads();
    for (int s = 128; s > 0; s >>= 1) {
        if (t < s) red[t] += red[t + s];
        __syncthreads();
    }
    float nrm = fmaxf(sqrtf(red[0]), 1e-12f);
    f_norm[b * D_DIM + t] = x / nrm;
    if (t < C_DIM) {
        float acc = bias[t];
        for (int d = 0; d < D_DIM; ++d) acc = fmaf(row[d], W[d * C_DIM + t], acc);
        float mx = acc;
        for (int off = 32; off > 0; off >>= 1) mx = fmaxf(mx, __shfl_xor(mx, off, 64));
        float e = expf(acc - mx);
        float ssum = e;
        for (int off = 32; off > 0; off >>= 1) ssum += __shfl_xor(ssum, off, 64);
        softm[b * C_DIM + t] = e / ssum;
    }
}

// one-shot: fea_bank (with f_norm substitution) -> pre-permuted bf16 32-cand chunks.
// Block cc handles rows 64cc..64cc+63 = chunk32s (2cc, 2cc+1).
__global__ __launch_bounds__(256) void k_convert(const float* __restrict__ fea_bank,
                                                 const float* __restrict__ f_norm,
                                                 const int* __restrict__ pos_of,
                                                 short* __restrict__ bank) {
    int cc = blockIdx.x, t = threadIdx.x;
    int r = t >> 2, q4 = t & 3;
    int n = cc * 64 + r;
    int p = pos_of[n];
    const float* src = (p >= 0) ? (f_norm + (size_t)p * D_DIM)
                                : (fea_bank + (size_t)n * D_DIM);
    short* dst = bank + (size_t)(cc * 2 + (r >> 5)) * CH32_SH;
    int rl = r & 31;
    #pragma unroll
    for (int i = 0; i < 8; ++i) {
        int kk = q4 * 64 + i * 8;
        float4 a = *(const float4*)(src + kk);
        float4 b = *(const float4*)(src + kk + 4);
        int e = ((kk >> 4) * 64) + (((kk >> 3) & 1) * 32) + rl;
        *(u16x8*)(dst + (size_t)e * 8) = pack8(a, b);
    }
}

// permute query rows into 64-row bf16 tiles (fragment order)
__global__ __launch_bounds__(256) void k_permq(const float* __restrict__ rows,
                                               const float* __restrict__ fea_bank,
                                               const int* __restrict__ idx,
                                               const int* __restrict__ pos_of,
                                               short* __restrict__ dst) {
    int tile = blockIdx.x, t = threadIdx.x;
    int r = t >> 2, q4 = t & 3;
    const float* src;
    if (idx) {
        int n = idx[tile * 64 + r];
        int p = pos_of[n];
        src = (p >= 0) ? (rows + (size_t)p * D_DIM) : (fea_bank + (size_t)n * D_DIM);
    } else {
        src = rows + (size_t)(tile * 64 + r) * D_DIM;
    }
    short* d = dst + (size_t)tile * QTILE_SH;
    #pragma unroll
    for (int i = 0; i < 8; ++i) {
        int kk = q4 * 64 + i * 8;
        float4 a = *(const float4*)(src + kk);
        float4 b = *(const float4*)(src + kk + 4);
        int e = ((kk >> 4) * 128) + ((r >> 5) * 64) + (((kk >> 3) & 1) * 32) + (r & 31);
        *(u16x8*)(d + (size_t)e * 8) = pack8(a, b);
    }
}

// MFMA distance + fused top-6 via packed u32 keys.
// 4 waves; each wave: 32 resident queries (64 VGPR, honest), 1 acc chain (16),
// 1 key list (6). 32-cand chunks (16KB), 32KB double-buffer -> 4 blocks/CU.
// acc init 2.0 => dots positive => IEEE bit order = value order.
// key = (bits & ~0x3FF) | (1023 - pos), pos = ch*32 + m (job-local).
__global__ __launch_bounds__(256, 4) void dist_topk(const short* __restrict__ qbf,
                                                    const short* __restrict__ bank,
                                                    float* __restrict__ pval,
                                                    int* __restrict__ pidx,
                                                    int nqt, int swz,
                                                    int S, int nchj) {
    __shared__ __align__(16) short sbuf[2 * CH32_SH];   // 32 KB double buffer

    int slab, qt;
    if (swz) {
        int bid = blockIdx.x;
        int xcd = bid & 7;
        int rem = bid >> 3;
        qt = rem % nqt;
        slab = (rem / nqt) * 8 + xcd;
        if (slab >= S) return;
    } else {
        slab = blockIdx.x;
        qt = blockIdx.y;
    }
    const int cfirst = slab * nchj;
    int nch = NCH32 - cfirst; if (nch > nchj) nch = nchj;

    const int t   = threadIdx.x;
    const int w   = t >> 6;
    const int l   = t & 63;
    const int khv = l >> 5;
    const int col = l & 31;

    // ---- B-frags: this wave's 32 queries, full K resident (16 x 4 VGPR) ----
    const short* qtile = qbf + (size_t)(qt * 2 + (w >> 1)) * QTILE_SH;
    const int half = w & 1;
    bf16x8 bfr[16];
    #pragma unroll
    for (int ks = 0; ks < 16; ++ks)
        bfr[ks] = *(const bf16x8*)(qtile + (size_t)(ks * 128 + half * 64 + l) * 8);

    unsigned kv[6];
    #pragma unroll
    for (int k = 0; k < 6; ++k) kv[k] = 0u;

    const short* sbase = bank + (size_t)cfirst * CH32_SH;

    // ---- prologue: issue loads(0) into buf 0 (4 x 16B per thread) ----
    #pragma unroll
    for (int i = 0; i < 4; ++i) {
        const short* gp = sbase + (size_t)(i * 256 + t) * 8;
        short* lp = sbuf + (size_t)(i * 256 + w * 64) * 8;
        __builtin_amdgcn_global_load_lds(
            (const __attribute__((address_space(1))) void*)gp,
            (__attribute__((address_space(3))) void*)lp, 16, 0, 0);
    }

    for (int ch = 0; ch < nch; ++ch) {
        const int cur = ch & 1;
        if (ch + 1 < nch) {
            const short* g = sbase + (size_t)(ch + 1) * CH32_SH;
            short* lbase = sbuf + (size_t)(cur ^ 1) * CH32_SH;
            #pragma unroll
            for (int i = 0; i < 4; ++i) {
                const short* gp = g + (size_t)(i * 256 + t) * 8;
                short* lp = lbase + (size_t)(i * 256 + w * 64) * 8;
                __builtin_amdgcn_global_load_lds(
                    (const __attribute__((address_space(1))) void*)gp,
                    (__attribute__((address_space(3))) void*)lp, 16, 0, 0);
            }
            asm volatile("s_waitcnt vmcnt(4)" ::: "memory");
        } else {
            asm volatile("s_waitcnt vmcnt(0)" ::: "memory");
        }
        __builtin_amdgcn_s_barrier();
        __builtin_amdgcn_sched_barrier(0);

        const short* cb = sbuf + (size_t)cur * CH32_SH;

        f32x16 a;
        #pragma unroll
        for (int i = 0; i < 16; ++i) a[i] = 2.0f;
        #pragma unroll
        for (int ks = 0; ks < 16; ++ks) {
            bf16x8 fa = *(const bf16x8*)(cb + (size_t)(ks * 64 + l) * 8);
            a = __builtin_amdgcn_mfma_f32_32x32x16_bf16(fa, bfr[ks], a, 0, 0, 0);
        }

        const unsigned invb = 1023u - (unsigned)(ch * 32);
        #pragma unroll
        for (int r = 0; r < 16; ++r) {
            unsigned m = (unsigned)((r & 3) + 8 * (r >> 2) + 4 * khv);
            unsigned x = (__float_as_uint(a[r]) & 0xFFFFFC00u) | (invb - m);
            kinsert(kv, x);
        }

        __builtin_amdgcn_sched_barrier(0);
        __builtin_amdgcn_s_barrier();
    }

    // ---- decode + direct global write: 2 lanes (khv) per query ----
    {
        int q = qt * 128 + w * 32 + col;
        size_t b0 = ((size_t)q * S + slab) * 12 + khv * 6;
        #pragma unroll
        for (int k = 0; k < 6; ++k) {
            unsigned key = kv[k];
            int pos = 1023 - (int)(key & 1023u);
            int c = pos >> 5, m = pos & 31;
            pval[b0 + k] = __uint_as_float(key & 0xFFFFFC00u);
            pidx[b0 + k] = (cfirst + c) * CH32 + m;
        }
    }
}

__global__ __launch_bounds__(256) void topk_merge(const float* __restrict__ pval,
                                                  const int* __restrict__ pidx,
                                                  int* __restrict__ out_idx,
                                                  int S) {
    int q = blockIdx.x, t = threadIdx.x;
    const int total = S * 12;
    float lv[6]; int li[6];
    #pragma unroll
    for (int k = 0; k < 6; ++k) { lv[k] = -3.4e38f; li[k] = 0x7fffffff; }
    size_t base = (size_t)q * total;
    for (int e = t; e < total; e += 256) insert6f(lv, li, pval[base + e], pidx[base + e]);
    __shared__ float sv[256][6];
    __shared__ int   si[256][6];
    #pragma unroll
    for (int k = 0; k < 6; ++k) { sv[t][k] = lv[k]; si[t][k] = li[k]; }
    __syncthreads();
    for (int w = 128; w >= 1; w >>= 1) {
        if (t < w) {
            float ov[6]; int oi[6];
            merge6(sv[t], si[t], sv[t + w], si[t + w], ov, oi);
            #pragma unroll
            for (int k = 0; k < 6; ++k) { sv[t][k] = ov[k]; si[t][k] = oi[k]; }
        }
        __syncthreads();
    }
    if (t == 0) {
        for (int k = 1; k < 6; ++k) out_idx[q * K_TOP + k - 1] = si[0][k];
    }
}

__global__ void k_loss(const float* __restrict__ softm, const float* __restrict__ score_bank,
                       const int* __restrict__ pos_of, const int* __restrict__ idx_near,
                       const int* __restrict__ idx_nn, const int* __restrict__ trg,
                       float* accp) {
    int b = blockIdx.x, c = threadIdx.x;   // 64 threads
    float p_bc = softm[b * C_DIM + c];
    float part = 0.f;
    for (int k = 0; k < K_TOP; ++k) {
        for (int j = 0; j < K_TOP; ++j) {
            int n = idx_nn[(b * K_TOP + k) * K_TOP + j];
            int p = pos_of[n];
            const float* srow = (p >= 0) ? (softm + (size_t)p * C_DIM)
                                         : (score_bank + (size_t)n * C_DIM);
            float s = srow[c];
            float v = s * (logf(s) - p_bc);
            for (int off = 32; off > 0; off >>= 1) v += __shfl_down(v, off, 64);
            if (c == 0) part += 0.1f * v;
        }
    }
    for (int k = 0; k < K_TOP; ++k) {
        int n = idx_near[b * K_TOP + k];
        int p = pos_of[n];
        const float* srow = (p >= 0) ? (softm + (size_t)p * C_DIM)
                                     : (score_bank + (size_t)n * C_DIM);
        float s = srow[c];
        float v = s * (logf(s) - p_bc);
        for (int off = 32; off > 0; off >>= 1) v += __shfl_down(v, off, 64);
        if (c == 0) {
            int m = 0;
            for (int j = 0; j < K_TOP; ++j)
                m += (idx_nn[(b * K_TOP + k) * K_TOP + j] == trg[b]) ? 1 : 0;
            float w = (m > 0) ? (float)m : 0.1f;
            part += w * v;
        }
    }
    if (c == 0) atomicAdd(accp, part * (1.0f / (float)B_SZ));
}

__global__ void k_final(const float* __restrict__ softm, const float* __restrict__ accp,
                        float* __restrict__ out) {
    int c = threadIdx.x;   // 64
    float m = 0.f;
    for (int b = 0; b < B_SZ; ++b) m += softm[b * C_DIM + c];
    m *= (1.0f / (float)B_SZ);
    float g = m * logf(m + 1e-5f);
    for (int off = 32; off > 0; off >>= 1) g += __shfl_down(g, off, 64);
    if (c == 0) out[0] = accp[0] + g;
}

extern "C" void kernel_launch(void* const* d_in, const int* in_sizes, int n_in,
                              void* d_out, int out_size, void* d_ws, size_t ws_size,
                              hipStream_t stream) {
    const float* features   = (const float*)d_in[0];
    const float* W          = (const float*)d_in[1];
    const float* bias       = (const float*)d_in[2];
    const float* fea_bank   = (const float*)d_in[3];
    const float* score_bank = (const float*)d_in[4];
    const int*   trg        = (const int*)d_in[5];
    float* out = (float*)d_out;

    char* ws = (char*)d_ws;
    size_t off = 0;
    auto alloc = [&](size_t bytes) -> void* {
        void* p = ws + off;
        off = (off + bytes + 255) & ~(size_t)255;
        return p;
    };
    short* bankbf   = (short*)alloc((size_t)NCH32 * CH32_SH * 2);            // 102.4 MB
    short* q1bf     = (short*)alloc((size_t)(B_SZ / 64) * QTILE_SH * 2);     // 128 KB
    short* q2bf     = (short*)alloc((size_t)(B_SZ * K_TOP / 64) * QTILE_SH * 2); // 640 KB
    float* f_norm   = (float*)alloc((size_t)B_SZ * D_DIM * 4);
    float* softm    = (float*)alloc((size_t)B_SZ * C_DIM * 4);
    int*   pos_of   = (int*)alloc((size_t)N_CAND * 4);
    float* accp     = (float*)alloc(4);
    int*   idx_near = (int*)alloc((size_t)B_SZ * K_TOP * 4);
    int*   idx_nn   = (int*)alloc((size_t)B_SZ * K_TOP * K_TOP * 4);
    float* pv1      = (float*)alloc((size_t)B_SZ * S1 * 12 * 4);
    int*   pi1      = (int*)alloc((size_t)B_SZ * S1 * 12 * 4);
    float* pv2      = (float*)alloc((size_t)B_SZ * K_TOP * S2 * 12 * 4);
    int*   pi2      = (int*)alloc((size_t)B_SZ * K_TOP * S2 * 12 * 4);

    k_init<<<dim3((N_CAND + 255) / 256), dim3(256), 0, stream>>>(pos_of, accp);
    k_scatter<<<dim3(1), dim3(256), 0, stream>>>(trg, pos_of);
    k_prep<<<dim3(B_SZ), dim3(256), 0, stream>>>(features, W, bias, f_norm, softm);

    k_convert<<<dim3(NCH32 / 2), dim3(256), 0, stream>>>(fea_bank, f_norm, pos_of, bankbf);
    k_permq<<<dim3(B_SZ / 64), dim3(256), 0, stream>>>(f_norm, fea_bank, nullptr, pos_of, q1bf);

    // pass 1: 256 queries = 2 qtiles of 128; 16-chunk jobs
    dist_topk<<<dim3(S1, 2), dim3(256), 0, stream>>>(
        q1bf, bankbf, pv1, pi1, 2, 0, S1, NCHJ1);
    topk_merge<<<dim3(B_SZ), dim3(256), 0, stream>>>(pv1, pi1, idx_near, S1);

    k_permq<<<dim3(B_SZ * K_TOP / 64), dim3(256), 0, stream>>>(
        f_norm, fea_bank, idx_near, pos_of, q2bf);

    // pass 2: 1280 queries = 10 qtiles of 128; 32-chunk jobs, XCD-grouped
    {
        int nqt = (B_SZ * K_TOP) / 128;           // 10
        int nsg = (S2 + 7) / 8;                   // 25
        dist_topk<<<dim3(nsg * 8 * nqt), dim3(256), 0, stream>>>(
            q2bf, bankbf, pv2, pi2, nqt, 1, S2, NCHJ2);
    }
    topk_merge<<<dim3(B_SZ * K_TOP), dim3(256), 0, stream>>>(pv2, pi2, idx_nn, S2);

    k_loss<<<dim3(B_SZ), dim3(64), 0, stream>>>(softm, score_bank, pos_of, idx_near, idx_nn, trg, accp);
    k_final<<<dim3(1), dim3(64), 0, stream>>>(softm, accp, out);
}